// Round 1
// baseline (2748.149 us; speedup 1.0000x reference)
//
#include <hip/hip_runtime.h>
#include <cstdint>
#include <cstddef>

// Problem constants (from reference)
#define NDST0 67584
#define NDST1 6144
#define NDST2 1024
#define NEDGE0 1013760
#define NEDGE1 61440
#define NEDGE2 5120
#define F0 128   // IN_FEATS
#define F1 256   // N_HIDDEN
#define NCLS 47

// ---------------------------------------------------------------------------
// Edge scatter: agg[dst] += table[idx ? idx[src] : src], deg[dst] += 1
// tpe = feat/4 threads cooperate per edge, each doing a float4 load + 4 atomics.
// ---------------------------------------------------------------------------
__global__ __launch_bounds__(256) void scatter_kernel(
    const float* __restrict__ table, const int* __restrict__ idx,
    const int* __restrict__ src, const int* __restrict__ dst,
    int nedge, int feat, int tpe_shift,
    float* __restrict__ agg, float* __restrict__ deg)
{
    const int tpe = 1 << tpe_shift;
    const int epb = 256 >> tpe_shift;
    const int e = blockIdx.x * epb + ((int)threadIdx.x >> tpe_shift);
    if (e >= nedge) return;
    const int lane = (int)threadIdx.x & (tpe - 1);
    const int s = src[e];
    const int d = dst[e];
    const int row = idx ? idx[s] : s;
    const float4 v = *(const float4*)(table + (size_t)row * feat + lane * 4);
    float* ap = agg + (size_t)d * feat + lane * 4;
    atomicAdd(ap + 0, v.x);
    atomicAdd(ap + 1, v.y);
    atomicAdd(ap + 2, v.z);
    atomicAdd(ap + 3, v.w);
    if (lane == 0) atomicAdd(deg + d, 1.0f);
}

// ---------------------------------------------------------------------------
// Fused SAGE layer GEMM:
//   out[m,n] = act( sum_k table[row(m),k]*Wself[k,n]
//                 + sum_k (agg[m,k]/max(deg[m],1))*Wneigh[k,n] + b[n] )
// row(m) = idx ? idx[m] : m.  Tile 64x64, BK=16, 4x4 per thread, 256 threads.
// K-loop runs over 2*din: first din = self phase, second din = neigh phase.
// LDS rows padded to 68 floats: all read/write patterns are <=2-way (free).
// ---------------------------------------------------------------------------
__global__ __launch_bounds__(256) void sage_gemm(
    const float* __restrict__ table, const int* __restrict__ idx,
    const float* __restrict__ agg, const float* __restrict__ deg,
    const float* __restrict__ Wself, const float* __restrict__ Wneigh,
    const float* __restrict__ bias, float* __restrict__ out,
    int dout, int din, int do_relu)
{
    __shared__ float As[16][68];
    __shared__ float Bs[16][68];

    const int tid = threadIdx.x;
    const int m0 = blockIdx.x * 64;
    const int n0 = blockIdx.y * 64;

    const int tm = tid >> 4;          // 0..15 -> output rows tm*4..+3
    const int tn = tid & 15;          // 0..15 -> output cols tn*4..+3

    // A loader: 64 rows x 16 k; thread -> (row, k-quad)
    const int lrow = tid >> 2;        // 0..63
    const int lk4  = (tid & 3) << 2;  // 0,4,8,12
    // B loader: 16 k x 64 n; thread -> (k, n-quad)
    const int bkk  = tid >> 4;        // 0..15
    const int bn4  = (tid & 15) << 2; // 0..60

    const int gmA = m0 + lrow;
    const long rowA = idx ? (long)idx[gmA] : (long)gmA;
    const float scale = 1.0f / fmaxf(deg[gmA], 1.0f);
    const float* tptr = table + rowA * din;
    const float* aptr = agg + (size_t)gmA * din;

    float acc[4][4] = {};

    const int K2 = 2 * din;
    for (int k0 = 0; k0 < K2; k0 += 16) {
        const bool self_phase = (k0 < din);
        // --- stage A fragment (registers) ---
        float4 av;
        if (self_phase) {
            av = *(const float4*)(tptr + k0 + lk4);
        } else {
            av = *(const float4*)(aptr + (k0 - din) + lk4);
            av.x *= scale; av.y *= scale; av.z *= scale; av.w *= scale;
        }
        // --- stage B fragment (registers) ---
        const float* W = self_phase ? Wself : Wneigh;
        const int kb = (self_phase ? k0 : (k0 - din)) + bkk;
        const float* wp = W + (size_t)kb * dout + n0 + bn4;
        float bv0, bv1, bv2, bv3;
        if (n0 + bn4 + 3 < dout) {
            const float4 w4 = *(const float4*)wp;
            bv0 = w4.x; bv1 = w4.y; bv2 = w4.z; bv3 = w4.w;
        } else {
            bv0 = (n0 + bn4 + 0 < dout) ? wp[0] : 0.0f;
            bv1 = (n0 + bn4 + 1 < dout) ? wp[1] : 0.0f;
            bv2 = (n0 + bn4 + 2 < dout) ? wp[2] : 0.0f;
            bv3 = (n0 + bn4 + 3 < dout) ? wp[3] : 0.0f;
        }

        __syncthreads();   // previous iteration's compute done
        As[lk4 + 0][lrow] = av.x;
        As[lk4 + 1][lrow] = av.y;
        As[lk4 + 2][lrow] = av.z;
        As[lk4 + 3][lrow] = av.w;
        Bs[bkk][bn4 + 0] = bv0;
        Bs[bkk][bn4 + 1] = bv1;
        Bs[bkk][bn4 + 2] = bv2;
        Bs[bkk][bn4 + 3] = bv3;
        __syncthreads();

        #pragma unroll
        for (int kk = 0; kk < 16; ++kk) {
            const float4 a4 = *(const float4*)&As[kk][tm << 2];
            const float4 b4 = *(const float4*)&Bs[kk][tn << 2];
            const float a_[4] = {a4.x, a4.y, a4.z, a4.w};
            const float b_[4] = {b4.x, b4.y, b4.z, b4.w};
            #pragma unroll
            for (int i = 0; i < 4; ++i)
                #pragma unroll
                for (int j = 0; j < 4; ++j)
                    acc[i][j] += a_[i] * b_[j];
        }
    }

    #pragma unroll
    for (int i = 0; i < 4; ++i) {
        const size_t gm = m0 + (tm << 2) + i;
        #pragma unroll
        for (int j = 0; j < 4; ++j) {
            const int gn = n0 + (tn << 2) + j;
            if (gn < dout) {
                float v = acc[i][j] + bias[gn];
                if (do_relu) v = fmaxf(v, 0.0f);
                out[gm * dout + gn] = v;
            }
        }
    }
}

// ---------------------------------------------------------------------------
extern "C" void kernel_launch(void* const* d_in, const int* in_sizes, int n_in,
                              void* d_out, int out_size, void* d_ws, size_t ws_size,
                              hipStream_t stream)
{
    const float* emb         = (const float*)d_in[0];
    const int*   input_nodes = (const int*)d_in[1];
    const int*   src0 = (const int*)d_in[2];
    const int*   dst0 = (const int*)d_in[3];
    const int*   src1 = (const int*)d_in[4];
    const int*   dst1 = (const int*)d_in[5];
    const int*   src2 = (const int*)d_in[6];
    const int*   dst2 = (const int*)d_in[7];
    const float* Ws0 = (const float*)d_in[8];
    const float* Wn0 = (const float*)d_in[9];
    const float* b0  = (const float*)d_in[10];
    const float* Ws1 = (const float*)d_in[11];
    const float* Wn1 = (const float*)d_in[12];
    const float* b1  = (const float*)d_in[13];
    const float* Ws2 = (const float*)d_in[14];
    const float* Wn2 = (const float*)d_in[15];
    const float* b2  = (const float*)d_in[16];
    float* out = (float*)d_out;

    // Workspace layout (floats). Zero-region (aggs+degs) first, then h1/h2.
    float* ws   = (float*)d_ws;
    float* agg0 = ws;                                   // 67584*128
    float* deg0 = agg0 + (size_t)NDST0 * F0;            // 67584
    float* agg1 = deg0 + NDST0;                         // 6144*256
    float* deg1 = agg1 + (size_t)NDST1 * F1;            // 6144
    float* agg2 = deg1 + NDST1;                         // 1024*256
    float* deg2 = agg2 + (size_t)NDST2 * F1;            // 1024
    float* h1   = deg2 + NDST2;                         // 67584*256
    float* h2   = h1 + (size_t)NDST0 * F1;              // 6144*256

    const size_t zero_bytes = (size_t)((deg2 + NDST2) - ws) * sizeof(float);
    hipMemsetAsync(d_ws, 0, zero_bytes, stream);

    // ---- Layer 0: din=128 ----
    scatter_kernel<<<NEDGE0 / 8, 256, 0, stream>>>(
        emb, input_nodes, src0, dst0, NEDGE0, F0, /*tpe_shift=*/5, agg0, deg0);
    sage_gemm<<<dim3(NDST0 / 64, 256 / 64), 256, 0, stream>>>(
        emb, input_nodes, agg0, deg0, Ws0, Wn0, b0, h1, /*dout=*/256, /*din=*/F0, /*relu=*/1);

    // ---- Layer 1: din=256 ----
    scatter_kernel<<<NEDGE1 / 4, 256, 0, stream>>>(
        h1, nullptr, src1, dst1, NEDGE1, F1, /*tpe_shift=*/6, agg1, deg1);
    sage_gemm<<<dim3(NDST1 / 64, 256 / 64), 256, 0, stream>>>(
        h1, nullptr, agg1, deg1, Ws1, Wn1, b1, h2, /*dout=*/256, /*din=*/F1, /*relu=*/1);

    // ---- Layer 2: din=256, dout=47, no relu, straight to d_out ----
    scatter_kernel<<<NEDGE2 / 4, 256, 0, stream>>>(
        h2, nullptr, src2, dst2, NEDGE2, F1, /*tpe_shift=*/6, agg2, deg2);
    sage_gemm<<<dim3(NDST2 / 64, 1), 256, 0, stream>>>(
        h2, nullptr, agg2, deg2, Ws2, Wn2, b2, out, /*dout=*/NCLS, /*din=*/F1, /*relu=*/0);
}

// Round 2
// 1143.683 us; speedup vs baseline: 2.4029x; 2.4029x over previous
//
#include <hip/hip_runtime.h>
#include <cstdint>
#include <cstddef>

// Problem constants (from reference)
#define NDST0 67584
#define NDST1 6144
#define NDST2 1024
#define NEDGE0 1013760
#define NEDGE1 61440
#define NEDGE2 5120
#define F0 128   // IN_FEATS
#define F1 256   // N_HIDDEN
#define NCLS 47

// ---------------------------------------------------------------------------
// 1) Histogram of dst: cnt[dst[e]] += 1
// ---------------------------------------------------------------------------
__global__ __launch_bounds__(256) void hist_kernel(
    const int* __restrict__ dst, int nedge, int* __restrict__ cnt)
{
    int e = blockIdx.x * 256 + threadIdx.x;
    const int stride = gridDim.x * 256;
    for (; e < nedge; e += stride)
        atomicAdd(&cnt[dst[e]], 1);
}

// ---------------------------------------------------------------------------
// 2) Single-block exclusive scan of cnt[0..n) -> rs[0..n] and work[0..n)
//    1024 threads, each owns a contiguous chunk; Hillis-Steele over chunk sums.
// ---------------------------------------------------------------------------
__global__ __launch_bounds__(1024) void scan_kernel(
    const int* __restrict__ cnt, int n,
    int* __restrict__ rs, int* __restrict__ work)
{
    __shared__ int sums[1024];
    const int tid = threadIdx.x;
    const int L = (n + 1023) >> 10;
    const int lo = tid * L;
    const int hi = (lo + L < n) ? (lo + L) : n;
    int s = 0;
    for (int i = lo; i < hi; ++i) s += cnt[i];
    sums[tid] = s;
    __syncthreads();
    int v = s;
    for (int off = 1; off < 1024; off <<= 1) {
        int t = (tid >= off) ? sums[tid - off] : 0;
        __syncthreads();
        v += t;
        sums[tid] = v;
        __syncthreads();
    }
    int run = v - s;   // exclusive prefix of this thread's chunk
    for (int i = lo; i < hi; ++i) {
        rs[i] = run;
        work[i] = run;
        run += cnt[i];
    }
    if (tid == 1023) rs[n] = run;
}

// ---------------------------------------------------------------------------
// 3) Scatter edges into dst-sorted order; resolve input_nodes indirection once.
//    esrc[pos] = row index into `table` for this edge's source.
// ---------------------------------------------------------------------------
__global__ __launch_bounds__(256) void fill_kernel(
    const int* __restrict__ src, const int* __restrict__ dst,
    const int* __restrict__ idx, int nedge,
    int* __restrict__ work, int* __restrict__ esrc)
{
    int e = blockIdx.x * 256 + threadIdx.x;
    if (e >= nedge) return;
    const int s = src[e];
    const int row = idx ? idx[s] : s;
    const int p = atomicAdd(&work[dst[e]], 1);
    esrc[p] = row;
}

// ---------------------------------------------------------------------------
// 4) Per-dst gather-accumulate (no atomics). lanes = feat/4 threads per dst,
//    each holds one float4 accumulator. Pre-scales by 1/max(deg,1).
// ---------------------------------------------------------------------------
__global__ __launch_bounds__(256) void gather_kernel(
    const float* __restrict__ table, const int* __restrict__ esrc,
    const int* __restrict__ rs, const int* __restrict__ cnt,
    int nd, int feat, int lshift, float* __restrict__ agg)
{
    const int lanes = 1 << lshift;
    const int gpb = 256 >> lshift;
    const int d = blockIdx.x * gpb + ((int)threadIdx.x >> lshift);
    if (d >= nd) return;
    const int lane = (int)threadIdx.x & (lanes - 1);
    const int start = rs[d];
    const int c = cnt[d];
    const float* tb = table + (size_t)lane * 4;
    float4 acc = make_float4(0.f, 0.f, 0.f, 0.f);
    int i = 0;
    for (; i + 1 < c; i += 2) {   // 2-way unroll: two independent 512B loads
        const int r0 = esrc[start + i];
        const int r1 = esrc[start + i + 1];
        const float4 v0 = *(const float4*)(tb + (size_t)r0 * feat);
        const float4 v1 = *(const float4*)(tb + (size_t)r1 * feat);
        acc.x += v0.x + v1.x; acc.y += v0.y + v1.y;
        acc.z += v0.z + v1.z; acc.w += v0.w + v1.w;
    }
    if (i < c) {
        const int r0 = esrc[start + i];
        const float4 v0 = *(const float4*)(tb + (size_t)r0 * feat);
        acc.x += v0.x; acc.y += v0.y; acc.z += v0.z; acc.w += v0.w;
    }
    const float sc = 1.0f / fmaxf((float)c, 1.0f);
    float4 o = make_float4(acc.x * sc, acc.y * sc, acc.z * sc, acc.w * sc);
    *(float4*)(agg + (size_t)d * feat + lane * 4) = o;
}

// ---------------------------------------------------------------------------
// Fused SAGE layer GEMM:
//   out[m,n] = act( sum_k table[row(m),k]*Wself[k,n] + sum_k agg[m,k]*Wneigh[k,n] + b[n] )
// agg is PRE-SCALED by 1/deg. Tile 64x64, BK=16, 4x4/thread, 256 threads.
// ---------------------------------------------------------------------------
__global__ __launch_bounds__(256) void sage_gemm(
    const float* __restrict__ table, const int* __restrict__ idx,
    const float* __restrict__ agg,
    const float* __restrict__ Wself, const float* __restrict__ Wneigh,
    const float* __restrict__ bias, float* __restrict__ out,
    int dout, int din, int do_relu)
{
    __shared__ float As[16][68];
    __shared__ float Bs[16][68];

    const int tid = threadIdx.x;
    const int m0 = blockIdx.x * 64;
    const int n0 = blockIdx.y * 64;

    const int tm = tid >> 4;
    const int tn = tid & 15;

    const int lrow = tid >> 2;
    const int lk4  = (tid & 3) << 2;
    const int bkk  = tid >> 4;
    const int bn4  = (tid & 15) << 2;

    const int gmA = m0 + lrow;
    const long rowA = idx ? (long)idx[gmA] : (long)gmA;
    const float* tptr = table + rowA * din;
    const float* aptr = agg + (size_t)gmA * din;

    float acc[4][4] = {};

    const int K2 = 2 * din;
    for (int k0 = 0; k0 < K2; k0 += 16) {
        const bool self_phase = (k0 < din);
        float4 av;
        if (self_phase) {
            av = *(const float4*)(tptr + k0 + lk4);
        } else {
            av = *(const float4*)(aptr + (k0 - din) + lk4);
        }
        const float* W = self_phase ? Wself : Wneigh;
        const int kb = (self_phase ? k0 : (k0 - din)) + bkk;
        const float* wp = W + (size_t)kb * dout + n0 + bn4;
        float bv0, bv1, bv2, bv3;
        if (n0 + bn4 + 3 < dout) {
            const float4 w4 = *(const float4*)wp;
            bv0 = w4.x; bv1 = w4.y; bv2 = w4.z; bv3 = w4.w;
        } else {
            bv0 = (n0 + bn4 + 0 < dout) ? wp[0] : 0.0f;
            bv1 = (n0 + bn4 + 1 < dout) ? wp[1] : 0.0f;
            bv2 = (n0 + bn4 + 2 < dout) ? wp[2] : 0.0f;
            bv3 = (n0 + bn4 + 3 < dout) ? wp[3] : 0.0f;
        }

        __syncthreads();
        As[lk4 + 0][lrow] = av.x;
        As[lk4 + 1][lrow] = av.y;
        As[lk4 + 2][lrow] = av.z;
        As[lk4 + 3][lrow] = av.w;
        Bs[bkk][bn4 + 0] = bv0;
        Bs[bkk][bn4 + 1] = bv1;
        Bs[bkk][bn4 + 2] = bv2;
        Bs[bkk][bn4 + 3] = bv3;
        __syncthreads();

        #pragma unroll
        for (int kk = 0; kk < 16; ++kk) {
            const float4 a4 = *(const float4*)&As[kk][tm << 2];
            const float4 b4 = *(const float4*)&Bs[kk][tn << 2];
            const float a_[4] = {a4.x, a4.y, a4.z, a4.w};
            const float b_[4] = {b4.x, b4.y, b4.z, b4.w};
            #pragma unroll
            for (int i = 0; i < 4; ++i)
                #pragma unroll
                for (int j = 0; j < 4; ++j)
                    acc[i][j] += a_[i] * b_[j];
        }
    }

    #pragma unroll
    for (int i = 0; i < 4; ++i) {
        const size_t gm = m0 + (tm << 2) + i;
        #pragma unroll
        for (int j = 0; j < 4; ++j) {
            const int gn = n0 + (tn << 2) + j;
            if (gn < dout) {
                float v = acc[i][j] + bias[gn];
                if (do_relu) v = fmaxf(v, 0.0f);
                out[gm * dout + gn] = v;
            }
        }
    }
}

// ---------------------------------------------------------------------------
extern "C" void kernel_launch(void* const* d_in, const int* in_sizes, int n_in,
                              void* d_out, int out_size, void* d_ws, size_t ws_size,
                              hipStream_t stream)
{
    const float* emb         = (const float*)d_in[0];
    const int*   input_nodes = (const int*)d_in[1];
    const int*   src0 = (const int*)d_in[2];
    const int*   dst0 = (const int*)d_in[3];
    const int*   src1 = (const int*)d_in[4];
    const int*   dst1 = (const int*)d_in[5];
    const int*   src2 = (const int*)d_in[6];
    const int*   dst2 = (const int*)d_in[7];
    const float* Ws0 = (const float*)d_in[8];
    const float* Wn0 = (const float*)d_in[9];
    const float* b0  = (const float*)d_in[10];
    const float* Ws1 = (const float*)d_in[11];
    const float* Wn1 = (const float*)d_in[12];
    const float* b1  = (const float*)d_in[13];
    const float* Ws2 = (const float*)d_in[14];
    const float* Wn2 = (const float*)d_in[15];
    const float* b2  = (const float*)d_in[16];
    float* out = (float*)d_out;

    // ---- Workspace layout ----
    float* ws   = (float*)d_ws;
    float* agg0 = ws;                                   // 67584*128
    float* agg1 = agg0 + (size_t)NDST0 * F0;            // 6144*256
    float* agg2 = agg1 + (size_t)NDST1 * F1;            // 1024*256
    float* h1   = agg2 + (size_t)NDST2 * F1;            // 67584*256
    float* h2   = h1 + (size_t)NDST0 * F1;              // 6144*256

    int* ip    = (int*)(h2 + (size_t)NDST1 * F1);
    // zero region: the three histograms, contiguous
    int* cnt0  = ip;               ip += NDST0;
    int* cnt1  = ip;               ip += NDST1;
    int* cnt2  = ip;               ip += NDST2;
    const size_t zero_bytes = (size_t)(NDST0 + NDST1 + NDST2) * sizeof(int);
    int* rs0   = ip;               ip += NDST0 + 1;
    int* work0 = ip;               ip += NDST0;
    int* rs1   = ip;               ip += NDST1 + 1;
    int* work1 = ip;               ip += NDST1;
    int* rs2   = ip;               ip += NDST2 + 1;
    int* work2 = ip;               ip += NDST2;
    int* esrc0 = ip;               ip += NEDGE0;
    int* esrc1 = ip;               ip += NEDGE1;
    int* esrc2 = ip;               ip += NEDGE2;

    hipMemsetAsync(cnt0, 0, zero_bytes, stream);

    // ---- Layer 0: din=128 ----
    hist_kernel<<<1024, 256, 0, stream>>>(dst0, NEDGE0, cnt0);
    scan_kernel<<<1, 1024, 0, stream>>>(cnt0, NDST0, rs0, work0);
    fill_kernel<<<(NEDGE0 + 255) / 256, 256, 0, stream>>>(src0, dst0, input_nodes, NEDGE0, work0, esrc0);
    gather_kernel<<<(NDST0 + 7) / 8, 256, 0, stream>>>(emb, esrc0, rs0, cnt0, NDST0, F0, /*lshift=*/5, agg0);
    sage_gemm<<<dim3(NDST0 / 64, 256 / 64), 256, 0, stream>>>(
        emb, input_nodes, agg0, Ws0, Wn0, b0, h1, /*dout=*/256, /*din=*/F0, /*relu=*/1);

    // ---- Layer 1: din=256 ----
    hist_kernel<<<256, 256, 0, stream>>>(dst1, NEDGE1, cnt1);
    scan_kernel<<<1, 1024, 0, stream>>>(cnt1, NDST1, rs1, work1);
    fill_kernel<<<(NEDGE1 + 255) / 256, 256, 0, stream>>>(src1, dst1, nullptr, NEDGE1, work1, esrc1);
    gather_kernel<<<(NDST1 + 3) / 4, 256, 0, stream>>>(h1, esrc1, rs1, cnt1, NDST1, F1, /*lshift=*/6, agg1);
    sage_gemm<<<dim3(NDST1 / 64, 256 / 64), 256, 0, stream>>>(
        h1, nullptr, agg1, Ws1, Wn1, b1, h2, /*dout=*/256, /*din=*/F1, /*relu=*/1);

    // ---- Layer 2: din=256, dout=47, no relu, straight to d_out ----
    hist_kernel<<<64, 256, 0, stream>>>(dst2, NEDGE2, cnt2);
    scan_kernel<<<1, 1024, 0, stream>>>(cnt2, NDST2, rs2, work2);
    fill_kernel<<<(NEDGE2 + 255) / 256, 256, 0, stream>>>(src2, dst2, nullptr, NEDGE2, work2, esrc2);
    gather_kernel<<<(NDST2 + 3) / 4, 256, 0, stream>>>(h2, esrc2, rs2, cnt2, NDST2, F1, /*lshift=*/6, agg2);
    sage_gemm<<<dim3(NDST2 / 64, 1), 256, 0, stream>>>(
        h2, nullptr, agg2, Ws2, Wn2, b2, out, /*dout=*/NCLS, /*din=*/F1, /*relu=*/0);
}

// Round 3
// 1025.533 us; speedup vs baseline: 2.6797x; 1.1152x over previous
//
#include <hip/hip_runtime.h>
#include <cstdint>
#include <cstddef>

// Problem constants (from reference)
#define NDST0 67584
#define NDST1 6144
#define NDST2 1024
#define NEDGE0 1013760
#define NEDGE1 61440
#define NEDGE2 5120
#define F0 128   // IN_FEATS
#define F1 256   // N_HIDDEN
#define NCLS 47

typedef unsigned short ushort_t;
typedef __attribute__((ext_vector_type(8))) short short8;     // 8 bf16 (4 VGPRs) - MFMA A/B frag
typedef __attribute__((ext_vector_type(4))) float floatx4;    // MFMA C/D frag

// ---- bf16 <-> f32 helpers (RNE, no NaN inputs here) ----
__device__ __forceinline__ ushort_t f2bf(float f) {
    union { float f; unsigned u; } v; v.f = f;
    unsigned r = v.u + 0x7fffu + ((v.u >> 16) & 1u);
    return (ushort_t)(r >> 16);
}
__device__ __forceinline__ float bf2f(ushort_t u) {
    union { unsigned u; float f; } v; v.u = ((unsigned)u) << 16;
    return v.f;
}

// async global->LDS, 16B per lane (global_load_lds_dwordx4)
__device__ __forceinline__ void async_copy16(ushort_t* lds, const ushort_t* g) {
    __builtin_amdgcn_global_load_lds(
        (const __attribute__((address_space(1))) unsigned*)(g),
        (__attribute__((address_space(3))) unsigned*)(lds),
        16, 0, 0);
}

// ---------------------------------------------------------------------------
// 1) Histogram of dst
// ---------------------------------------------------------------------------
__global__ __launch_bounds__(256) void hist_kernel(
    const int* __restrict__ dst, int nedge, int* __restrict__ cnt)
{
    int e = blockIdx.x * 256 + threadIdx.x;
    const int stride = gridDim.x * 256;
    for (; e < nedge; e += stride)
        atomicAdd(&cnt[dst[e]], 1);
}

// ---------------------------------------------------------------------------
// 2) Single-block exclusive scan: cnt[0..n) -> rs[0..n], work[0..n)
// ---------------------------------------------------------------------------
__global__ __launch_bounds__(1024) void scan_kernel(
    const int* __restrict__ cnt, int n,
    int* __restrict__ rs, int* __restrict__ work)
{
    __shared__ int sums[1024];
    const int tid = threadIdx.x;
    const int L = (n + 1023) >> 10;
    const int lo = tid * L;
    const int hi = (lo + L < n) ? (lo + L) : n;
    int s = 0;
    for (int i = lo; i < hi; ++i) s += cnt[i];
    sums[tid] = s;
    __syncthreads();
    int v = s;
    for (int off = 1; off < 1024; off <<= 1) {
        int t = (tid >= off) ? sums[tid - off] : 0;
        __syncthreads();
        v += t;
        sums[tid] = v;
        __syncthreads();
    }
    int run = v - s;
    for (int i = lo; i < hi; ++i) {
        rs[i] = run;
        work[i] = run;
        run += cnt[i];
    }
    if (tid == 1023) rs[n] = run;
}

// ---------------------------------------------------------------------------
// 3) Scatter edges into dst-sorted order (resolve input_nodes once)
// ---------------------------------------------------------------------------
__global__ __launch_bounds__(256) void fill_kernel(
    const int* __restrict__ src, const int* __restrict__ dst,
    const int* __restrict__ idx, int nedge,
    int* __restrict__ work, int* __restrict__ esrc)
{
    int e = blockIdx.x * 256 + threadIdx.x;
    if (e >= nedge) return;
    const int s = src[e];
    const int row = idx ? idx[s] : s;
    const int p = atomicAdd(&work[dst[e]], 1);
    esrc[p] = row;
}

// ---------------------------------------------------------------------------
// 4a) Per-dst gather-accumulate from fp32 table -> bf16 agg (pre-scaled 1/deg)
//     lanes = feat/4, float4 per lane.
// ---------------------------------------------------------------------------
__global__ __launch_bounds__(256) void gather_f32(
    const float* __restrict__ table, const int* __restrict__ esrc,
    const int* __restrict__ rs, const int* __restrict__ cnt,
    int nd, int feat, int lshift, ushort_t* __restrict__ agg)
{
    const int lanes = 1 << lshift;
    const int gpb = 256 >> lshift;
    const int d = blockIdx.x * gpb + ((int)threadIdx.x >> lshift);
    if (d >= nd) return;
    const int lane = (int)threadIdx.x & (lanes - 1);
    const int start = rs[d];
    const int c = cnt[d];
    const float* tb = table + (size_t)lane * 4;
    float4 acc = make_float4(0.f, 0.f, 0.f, 0.f);
    int i = 0;
    for (; i + 1 < c; i += 2) {
        const int r0 = esrc[start + i];
        const int r1 = esrc[start + i + 1];
        const float4 v0 = *(const float4*)(tb + (size_t)r0 * feat);
        const float4 v1 = *(const float4*)(tb + (size_t)r1 * feat);
        acc.x += v0.x + v1.x; acc.y += v0.y + v1.y;
        acc.z += v0.z + v1.z; acc.w += v0.w + v1.w;
    }
    if (i < c) {
        const int r0 = esrc[start + i];
        const float4 v0 = *(const float4*)(tb + (size_t)r0 * feat);
        acc.x += v0.x; acc.y += v0.y; acc.z += v0.z; acc.w += v0.w;
    }
    const float sc = 1.0f / fmaxf((float)c, 1.0f);
    ushort4 o;
    o.x = f2bf(acc.x * sc); o.y = f2bf(acc.y * sc);
    o.z = f2bf(acc.z * sc); o.w = f2bf(acc.w * sc);
    *(ushort4*)(agg + (size_t)d * feat + lane * 4) = o;
}

// ---------------------------------------------------------------------------
// 4b) Same, but table is bf16 (h1/h2). lanes = feat/4, ushort4 per lane.
// ---------------------------------------------------------------------------
__global__ __launch_bounds__(256) void gather_bf16(
    const ushort_t* __restrict__ table, const int* __restrict__ esrc,
    const int* __restrict__ rs, const int* __restrict__ cnt,
    int nd, int feat, int lshift, ushort_t* __restrict__ agg)
{
    const int lanes = 1 << lshift;
    const int gpb = 256 >> lshift;
    const int d = blockIdx.x * gpb + ((int)threadIdx.x >> lshift);
    if (d >= nd) return;
    const int lane = (int)threadIdx.x & (lanes - 1);
    const int start = rs[d];
    const int c = cnt[d];
    const ushort_t* tb = table + (size_t)lane * 4;
    float ax = 0.f, ay = 0.f, az = 0.f, aw = 0.f;
    for (int i = 0; i < c; ++i) {
        const int r0 = esrc[start + i];
        const ushort4 v = *(const ushort4*)(tb + (size_t)r0 * feat);
        ax += bf2f(v.x); ay += bf2f(v.y); az += bf2f(v.z); aw += bf2f(v.w);
    }
    const float sc = 1.0f / fmaxf((float)c, 1.0f);
    ushort4 o;
    o.x = f2bf(ax * sc); o.y = f2bf(ay * sc);
    o.z = f2bf(az * sc); o.w = f2bf(aw * sc);
    *(ushort4*)(agg + (size_t)d * feat + lane * 4) = o;
}

// ---------------------------------------------------------------------------
// embsel[m][k] = bf16(emb[input_nodes[m]][k])  (one float4 quad per thread)
// ---------------------------------------------------------------------------
__global__ __launch_bounds__(256) void sel_convert(
    const float* __restrict__ emb, const int* __restrict__ idx,
    int m_total, int feat, ushort_t* __restrict__ outb)
{
    const int q = blockIdx.x * 256 + threadIdx.x;   // quad index
    const int qpr = feat >> 2;                      // quads per row
    if (q >= m_total * qpr) return;
    const int m = q / qpr;
    const int c = q - m * qpr;
    const int row = idx[m];
    const float4 v = *(const float4*)(emb + (size_t)row * feat + c * 4);
    ushort4 o;
    o.x = f2bf(v.x); o.y = f2bf(v.y); o.z = f2bf(v.z); o.w = f2bf(v.w);
    *(ushort4*)(outb + (size_t)m * feat + c * 4) = o;
}

// ---------------------------------------------------------------------------
// Wcat_t[n][k2] = bf16( k2 < din ? Wself[k2][n] : Wneigh[k2-din][n] )
// rows n >= dout are zero (padding for the N-tile).
// ---------------------------------------------------------------------------
__global__ __launch_bounds__(256) void wprep_kernel(
    const float* __restrict__ Ws, const float* __restrict__ Wn,
    int din, int dout, int npad, ushort_t* __restrict__ Bt)
{
    const int id = blockIdx.x * 256 + threadIdx.x;
    const int K2 = 2 * din;
    if (id >= npad * K2) return;
    const int n = id / K2;
    const int k2 = id - n * K2;
    float v = 0.f;
    if (n < dout)
        v = (k2 < din) ? Ws[(size_t)k2 * dout + n] : Wn[(size_t)(k2 - din) * dout + n];
    Bt[id] = f2bf(v);
}

// ---------------------------------------------------------------------------
// MFMA GEMM (m97 structure): 128x128 tile, 4 waves x (64x64), BK=32 bf16.
//   out[m,n] = act( sum_k Aself[m,k]*Wself[k,n] + sum_k Aneigh[m,k]*Wneigh[k,n] + b[n] )
// A-phase: k0 < din -> Aself, else Aneigh (phase-uniform pointer switch).
// B from pre-transposed Wcat_t [npad>=128 rows][K2], staged coalesced.
// ---------------------------------------------------------------------------
__global__ __launch_bounds__(256) void mfma_gemm(
    const ushort_t* __restrict__ Aself, const ushort_t* __restrict__ Aneigh,
    const ushort_t* __restrict__ Bt, const float* __restrict__ bias,
    void* __restrict__ outp, int din, int dout, int out_bf16, int do_relu)
{
    __shared__ ushort_t As[128 * 32];
    __shared__ ushort_t Bs[128 * 32];

    const int tid  = threadIdx.x;
    const int wave = tid >> 6;
    const int lane = tid & 63;
    const int m0 = blockIdx.x * 128;
    const int n0 = blockIdx.y * 128;
    const int wm = (wave & 1) * 64;
    const int wn = (wave >> 1) * 64;

    // staging: per wave 2 instrs x (16 rows x 64B); lane -> row l>>2, chunk l&3
    const int arow = lane >> 2;
    const int achk = (lane & 3) * 8;     // ushort offset of 16B chunk

    const int K2 = 2 * din;

    floatx4 acc[4][4];
    const floatx4 zero = {0.f, 0.f, 0.f, 0.f};
    #pragma unroll
    for (int i = 0; i < 4; ++i)
        #pragma unroll
        for (int j = 0; j < 4; ++j) acc[i][j] = zero;

    const int fr = lane & 15;
    const int fq = (lane >> 4) * 8;      // ushort offset of k-chunk in frag row

    for (int k0 = 0; k0 < K2; k0 += 32) {
        const ushort_t* Abase = (k0 < din) ? (Aself + k0) : (Aneigh + (k0 - din));
        #pragma unroll
        for (int i = 0; i < 2; ++i) {
            const int rg = (wave * 2 + i) * 16 + arow;           // tile row 0..127
            async_copy16(&As[rg * 32 + achk],
                         Abase + (size_t)(m0 + rg) * din + achk);
            async_copy16(&Bs[rg * 32 + achk],
                         Bt + (size_t)(n0 + rg) * K2 + k0 + achk);
        }
        __syncthreads();   // drains vmcnt: staged data visible

        short8 a[4], b[4];
        #pragma unroll
        for (int f = 0; f < 4; ++f) {
            a[f] = *(const short8*)&As[(wm + f * 16 + fr) * 32 + fq];
            b[f] = *(const short8*)&Bs[(wn + f * 16 + fr) * 32 + fq];
        }
        #pragma unroll
        for (int fm = 0; fm < 4; ++fm)
            #pragma unroll
            for (int fn = 0; fn < 4; ++fn)
                acc[fm][fn] = __builtin_amdgcn_mfma_f32_16x16x32_bf16(
                    a[fm], b[fn], acc[fm][fn], 0, 0, 0);
        __syncthreads();   // all waves done reading before next stage
    }

    // epilogue: C/D layout col=lane&15, row=(lane>>4)*4+reg  [m89/m91]
    const int erow = (lane >> 4) * 4;
    const int ecol = lane & 15;
    #pragma unroll
    for (int fn = 0; fn < 4; ++fn) {
        const int gn = n0 + wn + fn * 16 + ecol;
        if (gn >= dout) continue;
        const float bv = bias[gn];
        #pragma unroll
        for (int fm = 0; fm < 4; ++fm) {
            #pragma unroll
            for (int r = 0; r < 4; ++r) {
                const size_t gm = m0 + wm + fm * 16 + erow + r;
                float v = acc[fm][fn][r] + bv;
                if (do_relu) v = fmaxf(v, 0.f);
                if (out_bf16) ((ushort_t*)outp)[gm * dout + gn] = f2bf(v);
                else          ((float*)outp)[gm * dout + gn] = v;
            }
        }
    }
}

// ---------------------------------------------------------------------------
extern "C" void kernel_launch(void* const* d_in, const int* in_sizes, int n_in,
                              void* d_out, int out_size, void* d_ws, size_t ws_size,
                              hipStream_t stream)
{
    const float* emb         = (const float*)d_in[0];
    const int*   input_nodes = (const int*)d_in[1];
    const int*   src0 = (const int*)d_in[2];
    const int*   dst0 = (const int*)d_in[3];
    const int*   src1 = (const int*)d_in[4];
    const int*   dst1 = (const int*)d_in[5];
    const int*   src2 = (const int*)d_in[6];
    const int*   dst2 = (const int*)d_in[7];
    const float* Ws0 = (const float*)d_in[8];
    const float* Wn0 = (const float*)d_in[9];
    const float* b0  = (const float*)d_in[10];
    const float* Ws1 = (const float*)d_in[11];
    const float* Wn1 = (const float*)d_in[12];
    const float* b1  = (const float*)d_in[13];
    const float* Ws2 = (const float*)d_in[14];
    const float* Wn2 = (const float*)d_in[15];
    const float* b2  = (const float*)d_in[16];
    float* out = (float*)d_out;

    // ---- Workspace layout (bf16 activations + int CSR scratch) ----
    ushort_t* us     = (ushort_t*)d_ws;
    ushort_t* embsel = us;                                   // 67584*128
    ushort_t* agg0   = embsel + (size_t)NDST0 * F0;          // 67584*128
    ushort_t* h1     = agg0 + (size_t)NDST0 * F0;            // 67584*256
    ushort_t* agg1   = h1 + (size_t)NDST0 * F1;              // 6144*256
    ushort_t* h2     = agg1 + (size_t)NDST1 * F1;            // 6144*256
    ushort_t* agg2   = h2 + (size_t)NDST1 * F1;              // 1024*256
    ushort_t* Bt0    = agg2 + (size_t)NDST2 * F1;            // 256 x 256
    ushort_t* Bt1    = Bt0 + 256 * 256;                      // 256 x 512
    ushort_t* Bt2    = Bt1 + 256 * 512;                      // 128 x 512 (rows 47..127 zero)

    int* ip   = (int*)(Bt2 + 128 * 512);
    int* cnt0 = ip;  ip += NDST0;
    int* cnt1 = ip;  ip += NDST1;
    int* cnt2 = ip;  ip += NDST2;
    const size_t zero_bytes = (size_t)(NDST0 + NDST1 + NDST2) * sizeof(int);
    int* rs0   = ip; ip += NDST0 + 1;
    int* work0 = ip; ip += NDST0;
    int* rs1   = ip; ip += NDST1 + 1;
    int* work1 = ip; ip += NDST1;
    int* rs2   = ip; ip += NDST2 + 1;
    int* work2 = ip; ip += NDST2;
    int* esrc0 = ip; ip += NEDGE0;
    int* esrc1 = ip; ip += NEDGE1;
    int* esrc2 = ip; ip += NEDGE2;

    hipMemsetAsync(cnt0, 0, zero_bytes, stream);

    // Per-launch weight prep (cheap; must run every launch for graph capture)
    wprep_kernel<<<(256 * 256 + 255) / 256, 256, 0, stream>>>(Ws0, Wn0, F0, 256, 256, Bt0);
    wprep_kernel<<<(256 * 512 + 255) / 256, 256, 0, stream>>>(Ws1, Wn1, F1, 256, 256, Bt1);
    wprep_kernel<<<(128 * 512 + 255) / 256, 256, 0, stream>>>(Ws2, Wn2, F1, NCLS, 128, Bt2);

    // embsel = bf16(emb[input_nodes])
    sel_convert<<<(NDST0 * (F0 / 4) + 255) / 256, 256, 0, stream>>>(
        emb, input_nodes, NDST0, F0, embsel);

    // ---- Layer 0: din=128 ----
    hist_kernel<<<1024, 256, 0, stream>>>(dst0, NEDGE0, cnt0);
    scan_kernel<<<1, 1024, 0, stream>>>(cnt0, NDST0, rs0, work0);
    fill_kernel<<<(NEDGE0 + 255) / 256, 256, 0, stream>>>(src0, dst0, input_nodes, NEDGE0, work0, esrc0);
    gather_f32<<<NDST0 / 8, 256, 0, stream>>>(emb, esrc0, rs0, cnt0, NDST0, F0, 5, agg0);
    mfma_gemm<<<dim3(NDST0 / 128, 256 / 128), 256, 0, stream>>>(
        embsel, agg0, Bt0, b0, h1, F0, 256, /*out_bf16=*/1, /*relu=*/1);

    // ---- Layer 1: din=256 ----
    hist_kernel<<<256, 256, 0, stream>>>(dst1, NEDGE1, cnt1);
    scan_kernel<<<1, 1024, 0, stream>>>(cnt1, NDST1, rs1, work1);
    fill_kernel<<<(NEDGE1 + 255) / 256, 256, 0, stream>>>(src1, dst1, nullptr, NEDGE1, work1, esrc1);
    gather_bf16<<<NDST1 / 4, 256, 0, stream>>>(h1, esrc1, rs1, cnt1, NDST1, F1, 6, agg1);
    mfma_gemm<<<dim3(NDST1 / 128, 256 / 128), 256, 0, stream>>>(
        h1, agg1, Bt1, b1, h2, F1, 256, /*out_bf16=*/1, /*relu=*/1);

    // ---- Layer 2: din=256, dout=47, no relu, fp32 out ----
    hist_kernel<<<64, 256, 0, stream>>>(dst2, NEDGE2, cnt2);
    scan_kernel<<<1, 1024, 0, stream>>>(cnt2, NDST2, rs2, work2);
    fill_kernel<<<(NEDGE2 + 255) / 256, 256, 0, stream>>>(src2, dst2, nullptr, NEDGE2, work2, esrc2);
    gather_bf16<<<NDST2 / 4, 256, 0, stream>>>(h2, esrc2, rs2, cnt2, NDST2, F1, 6, agg2);
    mfma_gemm<<<dim3(NDST2 / 128, 1), 256, 0, stream>>>(
        h2, agg2, Bt2, b2, out, F1, NCLS, /*out_bf16=*/0, /*relu=*/0);
}